// Round 1
// baseline (1024.015 us; speedup 1.0000x reference)
//
#include <hip/hip_runtime.h>
#include <math.h>

#define TPB 256

// ---------------------------------------------------------------------------
// Problem geometry (fixed by the reference):
//   x: [8, 1, 128, 1024] f32
//   L0: CI=1,  CO=16, H=128, W=1024, pool -> 64x512
//   L1: CI=16, CO=32, H=64,  W=512,  pool -> 32x256
//   L2: CI=32, CO=48, H=32,  W=256,  pool -> 16x128
//   L3: CI=48, CO=64, H=16,  W=128,  no pool
//   L4: CI=64, CO=80, H=16,  W=128,  no pool -> d_out [8,80,16,128]
// ---------------------------------------------------------------------------

__global__ void zero_stats_kernel(double* st, int n) {
  int i = blockIdx.x * blockDim.x + threadIdx.x;
  if (i < n) st[i] = 0.0;
}

// Offsets = conv3x3(x, woff, pad=1) + boff; woff layout [18, CI, 3, 3].
template<int CI>
__global__ void offset_conv_kernel(const float* __restrict__ x,
                                   const float* __restrict__ woff,
                                   const float* __restrict__ boff,
                                   float* __restrict__ off,
                                   int B, int H, int W) {
  int idx = blockIdx.x * TPB + threadIdx.x;
  int total = B * H * W;
  if (idx >= total) return;
  int w = idx % W;
  int h = (idx / W) % H;
  int b = idx / (W * H);
  float acc[18];
#pragma unroll
  for (int j = 0; j < 18; j++) acc[j] = boff[j];
  const float* xb = x + (size_t)b * CI * H * W;
  for (int c = 0; c < CI; c++) {
    const float* xc = xb + (size_t)c * H * W;
#pragma unroll
    for (int t = 0; t < 9; t++) {
      int ky = t / 3, kx = t % 3;
      int yy = h - 1 + ky, xx = w - 1 + kx;
      float v = 0.f;
      if (yy >= 0 && yy < H && xx >= 0 && xx < W) v = xc[yy * W + xx];
#pragma unroll
      for (int j = 0; j < 18; j++)
        acc[j] += v * woff[(j * CI + c) * 9 + t];
    }
  }
  size_t base = ((size_t)b * 18) * H * W + (size_t)h * W + w;
#pragma unroll
  for (int j = 0; j < 18; j++)
    off[base + (size_t)j * H * W] = acc[j];
}

// Deformable conv main kernel.
// Block: 256 threads, handles PT consecutive pixels of one row h.
// Phase A: offsets into LDS (fused conv for layer 0, else load from off buffer)
// Phase B: bilinear sampling -> s_samp[(c*9+k)][p]
// Phase C: y[p][o] = sum_{c,k} samp * w   with weight chunks staged in LDS
template<int CI, int CO, int PT, int CG, bool FUSE_OFF>
__global__ __launch_bounds__(TPB) void deform_kernel(
    const float* __restrict__ x, const float* __restrict__ off,
    const float* __restrict__ woff, const float* __restrict__ boff,
    const float* __restrict__ wmain, float* __restrict__ out,
    int B, int H, int W) {
  constexpr int CG9 = CG * 9;
  constexpr int NCHUNK = CI / CG;
  constexpr int NOG = TPB / PT;   // o-groups
  constexpr int OS = CO / NOG;    // outputs per thread

  __shared__ float s_off[18 * PT];
  __shared__ float s_samp[CI * 9 * PT];
  __shared__ float s_wt[CO * CG9];

  const int tid = threadIdx.x;
  const int ntw = W / PT;
  const int tw = blockIdx.x % ntw;
  const int h = (blockIdx.x / ntw) % H;
  const int b = blockIdx.x / (ntw * H);
  const int w0 = tw * PT;
  const float* xb = x + (size_t)b * CI * H * W;

  if constexpr (FUSE_OFF) {
    // layer 0: CI == 1, compute the 18 offsets from a staged 3x(PT+2) patch
    __shared__ float s_xp[3][PT + 2];
    for (int t = tid; t < 3 * (PT + 2); t += TPB) {
      int r = t / (PT + 2), ci2 = t % (PT + 2);
      int yy = h - 1 + r, xx = w0 - 1 + ci2;
      float v = 0.f;
      if (yy >= 0 && yy < H && xx >= 0 && xx < W)
        v = x[((size_t)b * H + yy) * W + xx];
      s_xp[r][ci2] = v;
    }
    __syncthreads();
    for (int t = tid; t < 18 * PT; t += TPB) {
      int j = t / PT, p = t % PT;
      float a = boff[j];
#pragma unroll
      for (int ky = 0; ky < 3; ky++)
#pragma unroll
        for (int kx = 0; kx < 3; kx++)
          a += s_xp[ky][p + kx] * woff[j * 9 + ky * 3 + kx];
      s_off[j * PT + p] = a;
    }
  } else {
    const float* ob = off + ((size_t)b * 18 * H + h) * W + w0;
    for (int t = tid; t < 18 * PT; t += TPB) {
      int j = t / PT, p = t % PT;
      s_off[j * PT + p] = ob[(size_t)j * H * W + p];
    }
  }
  __syncthreads();

  // Phase B: sampling
  for (int pk = tid; pk < PT * 9; pk += TPB) {
    int p = pk % PT, k = pk / PT;
    int ky = k / 3, kx = k % 3;
    float dy = s_off[(2 * k) * PT + p];
    float dx = s_off[(2 * k + 1) * PT + p];
    float py = (float)(h - 1 + ky) + dy;
    float px = (float)(w0 + p - 1 + kx) + dx;
    float fy = floorf(py), fx = floorf(px);
    float wy = py - fy, wx = px - fx;
    int y0 = (int)fy, x0i = (int)fx;
    int y1 = y0 + 1, x1i = x0i + 1;
    bool vy0 = (y0 >= 0) && (y0 < H);
    bool vy1 = (y1 >= 0) && (y1 < H);
    bool vx0 = (x0i >= 0) && (x0i < W);
    bool vx1 = (x1i >= 0) && (x1i < W);
    int yc0 = min(max(y0, 0), H - 1), yc1 = min(max(y1, 0), H - 1);
    int xc0 = min(max(x0i, 0), W - 1), xc1 = min(max(x1i, 0), W - 1);
    float w00 = (vy0 && vx0) ? (1.f - wy) * (1.f - wx) : 0.f;
    float w01 = (vy0 && vx1) ? (1.f - wy) * wx : 0.f;
    float w10 = (vy1 && vx0) ? wy * (1.f - wx) : 0.f;
    float w11 = (vy1 && vx1) ? wy * wx : 0.f;
    int a00 = yc0 * W + xc0, a01 = yc0 * W + xc1;
    int a10 = yc1 * W + xc0, a11 = yc1 * W + xc1;
    for (int c = 0; c < CI; c++) {
      const float* xc = xb + (size_t)c * H * W;
      float v = xc[a00] * w00 + xc[a01] * w01 + xc[a10] * w10 + xc[a11] * w11;
      s_samp[(c * 9 + k) * PT + p] = v;
    }
  }

  // Phase C: per-pixel GEMM with LDS-staged weight chunks
  const int p = tid % PT, og = tid / PT;
  float acc[OS];
#pragma unroll
  for (int j = 0; j < OS; j++) acc[j] = 0.f;
  for (int cc = 0; cc < NCHUNK; cc++) {
    __syncthreads();
    for (int t = tid; t < CO * CG9; t += TPB) {
      int o = t / CG9, i = t % CG9;
      s_wt[t] = wmain[((size_t)o * CI + cc * CG) * 9 + i];
    }
    __syncthreads();
    const float* sp = s_samp + cc * CG9 * PT;
    const float* wt = s_wt + og * OS * CG9;
#pragma unroll 4
    for (int i = 0; i < CG9; i++) {
      float sv = sp[i * PT + p];
#pragma unroll
      for (int j = 0; j < OS; j++)
        acc[j] += sv * wt[j * CG9 + i];
    }
  }

  float* ob2 = out + (((size_t)b * CO) * H + h) * W + w0 + p;
#pragma unroll
  for (int j = 0; j < OS; j++)
    ob2[(size_t)(og * OS + j) * H * W] = acc[j];
}

// Per-channel sum / sumsq in f64 (biased var later).
__global__ void bn_stats_kernel(const float* __restrict__ y,
                                double* __restrict__ st,
                                int B, int C, int HW, int NB) {
  int c = blockIdx.x / NB;
  int sl = blockIdx.x % NB;
  int tid = threadIdx.x;
  double s = 0.0, s2 = 0.0;
  for (int b = 0; b < B; b++) {
    const float* p = y + ((size_t)b * C + c) * HW;
    for (int i = sl * TPB + tid; i < HW; i += NB * TPB) {
      float v = p[i];
      s += v;
      s2 += (double)v * (double)v;
    }
  }
  __shared__ double rs[TPB], rq[TPB];
  rs[tid] = s;
  rq[tid] = s2;
  __syncthreads();
  for (int o = TPB / 2; o > 0; o >>= 1) {
    if (tid < o) { rs[tid] += rs[tid + o]; rq[tid] += rq[tid + o]; }
    __syncthreads();
  }
  if (tid == 0) {
    atomicAdd(&st[2 * c], rs[0]);
    atomicAdd(&st[2 * c + 1], rq[0]);
  }
}

__global__ void bn_finalize_kernel(const double* __restrict__ st,
                                   const float* __restrict__ g,
                                   const float* __restrict__ bb,
                                   float* __restrict__ ss, int C, int N) {
  int c = threadIdx.x;
  if (c >= C) return;
  double mean = st[2 * c] / N;
  double var = st[2 * c + 1] / N - mean * mean;
  float inv = (float)(1.0 / sqrt(var + 1e-5));
  float sc = g[c] * inv;
  ss[c] = sc;
  ss[C + c] = bb[c] - (float)mean * sc;
}

__global__ void bn_apply_kernel(const float* __restrict__ y,
                                const float* __restrict__ ss,
                                float* __restrict__ out, int C, int HW, int n) {
  int i = blockIdx.x * TPB + threadIdx.x;
  if (i >= n) return;
  int c = (i / HW) % C;
  float v = fmaf(y[i], ss[c], ss[C + c]);
  out[i] = v > 0.f ? v : 0.01f * v;
}

__global__ void bn_apply_pool_kernel(const float* __restrict__ y,
                                     const float* __restrict__ ss,
                                     float* __restrict__ out,
                                     int C, int H, int W, int n) {
  int i = blockIdx.x * TPB + threadIdx.x;
  if (i >= n) return;
  int Wp = W >> 1, Hp = H >> 1;
  int pw = i % Wp;
  int ph = (i / Wp) % Hp;
  int c = (i / (Wp * Hp)) % C;
  int b = i / (Wp * Hp * C);
  const float* yp = y + (((size_t)b * C + c) * H + 2 * ph) * W + 2 * pw;
  float sc = ss[c], sh = ss[C + c];
  float v0 = fmaf(yp[0], sc, sh);     v0 = v0 > 0.f ? v0 : 0.01f * v0;
  float v1 = fmaf(yp[1], sc, sh);     v1 = v1 > 0.f ? v1 : 0.01f * v1;
  float v2 = fmaf(yp[W], sc, sh);     v2 = v2 > 0.f ? v2 : 0.01f * v2;
  float v3 = fmaf(yp[W + 1], sc, sh); v3 = v3 > 0.f ? v3 : 0.01f * v3;
  out[i] = fmaxf(fmaxf(v0, v1), fmaxf(v2, v3));
}

extern "C" void kernel_launch(void* const* d_in, const int* in_sizes, int n_in,
                              void* d_out, int out_size, void* d_ws, size_t ws_size,
                              hipStream_t stream) {
  const float* x = (const float*)d_in[0];
  const float *woff[5], *boff[5], *wm[5], *g[5], *bb[5];
  for (int i = 0; i < 5; i++) {
    woff[i] = (const float*)d_in[1 + 5 * i + 0];
    boff[i] = (const float*)d_in[1 + 5 * i + 1];
    wm[i]   = (const float*)d_in[1 + 5 * i + 2];
    g[i]    = (const float*)d_in[1 + 5 * i + 3];
    bb[i]   = (const float*)d_in[1 + 5 * i + 4];
  }

  // Workspace layout (floats):
  //   conv_buf : 16,777,216  (max conv out, layer0 [8,16,128,1024])
  //   off_buf  :  4,718,592  (max offsets, layer1 [8,18,64,512])
  //   xa       :  4,194,304  (x1 [8,16,64,512], reused for x3)
  //   xb2      :  2,097,152  (x2 [8,32,32,256], reused for x4)
  //   st       :   160 doubles, ss : 160 floats
  const size_t need = (size_t)(16777216 + 4718592 + 4194304 + 2097152) * 4 + 1280 + 640;
  if (ws_size < need) return;  // insufficient workspace -> visible validation failure

  float* conv_buf = (float*)d_ws;
  float* off_buf = conv_buf + 16777216;
  float* xa = off_buf + 4718592;
  float* xb2 = xa + 4194304;
  double* st = (double*)(xb2 + 2097152);
  float* ss = (float*)(st + 160);

  const int B = 8;

  auto bn = [&](const float* ybuf, int C, int H, int W, int NB,
                const float* gg, const float* bbb, float* outp, bool pool) {
    zero_stats_kernel<<<1, TPB, 0, stream>>>(st, 2 * C);
    bn_stats_kernel<<<C * NB, TPB, 0, stream>>>(ybuf, st, B, C, H * W, NB);
    bn_finalize_kernel<<<1, TPB, 0, stream>>>(st, gg, bbb, ss, C, B * H * W);
    if (pool) {
      int n = B * C * (H / 2) * (W / 2);
      bn_apply_pool_kernel<<<(n + TPB - 1) / TPB, TPB, 0, stream>>>(ybuf, ss, outp, C, H, W, n);
    } else {
      int n = B * C * H * W;
      bn_apply_kernel<<<(n + TPB - 1) / TPB, TPB, 0, stream>>>(ybuf, ss, outp, C, H * W, n);
    }
  };

  // ---- Layer 0: CI=1, CO=16, 128x1024, fused offsets, pool -> xa
  {
    const int H = 128, W = 1024;
    deform_kernel<1, 16, 64, 1, true><<<B * H * (W / 64), TPB, 0, stream>>>(
        x, nullptr, woff[0], boff[0], wm[0], conv_buf, B, H, W);
    bn(conv_buf, 16, H, W, 32, g[0], bb[0], xa, true);
  }
  // ---- Layer 1: CI=16, CO=32, 64x512, pool -> xb2
  {
    const int H = 64, W = 512;
    int n = B * H * W;
    offset_conv_kernel<16><<<(n + TPB - 1) / TPB, TPB, 0, stream>>>(
        xa, woff[1], boff[1], off_buf, B, H, W);
    deform_kernel<16, 32, 32, 8, false><<<B * H * (W / 32), TPB, 0, stream>>>(
        xa, off_buf, woff[1], boff[1], wm[1], conv_buf, B, H, W);
    bn(conv_buf, 32, H, W, 32, g[1], bb[1], xb2, true);
  }
  // ---- Layer 2: CI=32, CO=48, 32x256, pool -> xa
  {
    const int H = 32, W = 256;
    int n = B * H * W;
    offset_conv_kernel<32><<<(n + TPB - 1) / TPB, TPB, 0, stream>>>(
        xb2, woff[2], boff[2], off_buf, B, H, W);
    deform_kernel<32, 48, 32, 8, false><<<B * H * (W / 32), TPB, 0, stream>>>(
        xb2, off_buf, woff[2], boff[2], wm[2], conv_buf, B, H, W);
    bn(conv_buf, 48, H, W, 16, g[2], bb[2], xa, true);
  }
  // ---- Layer 3: CI=48, CO=64, 16x128, no pool -> xb2
  {
    const int H = 16, W = 128;
    int n = B * H * W;
    offset_conv_kernel<48><<<(n + TPB - 1) / TPB, TPB, 0, stream>>>(
        xa, woff[3], boff[3], off_buf, B, H, W);
    deform_kernel<48, 64, 32, 8, false><<<B * H * (W / 32), TPB, 0, stream>>>(
        xa, off_buf, woff[3], boff[3], wm[3], conv_buf, B, H, W);
    bn(conv_buf, 64, H, W, 8, g[3], bb[3], xb2, false);
  }
  // ---- Layer 4: CI=64, CO=80, 16x128, no pool -> d_out
  {
    const int H = 16, W = 128;
    int n = B * H * W;
    offset_conv_kernel<64><<<(n + TPB - 1) / TPB, TPB, 0, stream>>>(
        xb2, woff[4], boff[4], off_buf, B, H, W);
    deform_kernel<64, 80, 16, 8, false><<<B * H * (W / 16), TPB, 0, stream>>>(
        xb2, off_buf, woff[4], boff[4], wm[4], conv_buf, B, H, W);
    bn(conv_buf, 80, H, W, 8, g[4], bb[4], (float*)d_out, false);
  }
}